// Round 6
// baseline (109.799 us; speedup 1.0000x reference)
//
#include <hip/hip_runtime.h>
#include <math.h>

// Problem constants (match reference setup_inputs)
#define B_N   8192      // samples
#define Z_D   128       // feature dim
#define P_N   93        // proxies
#define NCLS  62        // classes
#define A_N   2730      // anchors: arange(0, 8189, 3)
#define BCAP  256       // class-bucket capacity (max expected ~180)
#define GT_S  96        // GT row stride
#define NBLK  256       // blocks (== CU count, all co-resident)
#define BLKT  512       // threads/block
#define MAGIC 0x5eedf00du
#define TWO_EPS   2e-6f
#define ZEPS2     (128.0f * 1e-6f * 1e-6f)

// Control-word atomics. Probes are relaxed LOADS (read-shared at the LLC —
// no exclusive-ownership serialization, unlike R5's fetch_add(0) probes).
// Arrivals are relaxed RMWs. Data uses PLAIN cached accesses; coherence is
// established in bulk: one __threadfence (buffer_wbl2) per block before
// arrival, one acquire load (buffer_inv) per block after the spin.
#define AT_LD(p)    __hip_atomic_load((p), __ATOMIC_RELAXED, __HIP_MEMORY_SCOPE_AGENT)
#define AT_LDA(p)   __hip_atomic_load((p), __ATOMIC_ACQUIRE, __HIP_MEMORY_SCOPE_AGENT)
#define AT_ST(p, v) __hip_atomic_store((p), (v), __ATOMIC_RELAXED, __HIP_MEMORY_SCOPE_AGENT)
#define AT_ADD(p, v) __hip_atomic_fetch_add((p), (v), __ATOMIC_RELAXED, __HIP_MEMORY_SCOPE_AGENT)

__device__ __forceinline__ float wave_sum(float v) {
#pragma unroll
  for (int off = 1; off < 64; off <<= 1) v += __shfl_xor(v, off, 64);
  return v;
}
__device__ __forceinline__ float wave_min(float v) {
#pragma unroll
  for (int off = 1; off < 64; off <<= 1) v = fminf(v, __shfl_xor(v, off, 64));
  return v;
}

__global__ __launch_bounds__(BLKT) void kFused(
    const float* __restrict__ z, const int* __restrict__ y_idx,
    const float* __restrict__ prox, const int* __restrict__ y_map,
    float* __restrict__ out,
    unsigned int* flag, unsigned int* bar0, unsigned int* bar1, float* accf,
    float* __restrict__ pp, float* __restrict__ sp,
    float* __restrict__ zz, float* __restrict__ sz, float* __restrict__ w,
    int* __restrict__ cnt, int* __restrict__ bkt, float* __restrict__ GT) {
  __shared__ float pt[6 * Z_D];            // P1 proxy tile (3 KB)
  __shared__ float lpp[P_N], lsp[P_N];     // P2 proxy scalars
  __shared__ int lymap[NCLS];
  __shared__ float part[8];
  __shared__ int lcnt;
  const int b = blockIdx.x, tid = threadIdx.x;
  const int lane = tid & 63, wv = tid >> 6;

  // --- init (block 0): zero control words, publish MAGIC after drain.
  // ws poisoned 0xAA pre-launch; 0xAAAAAAAA != MAGIC so protocol is safe.
  if (b == 0 && tid == 0) {
    AT_ST(bar0, 0u); AT_ST(bar1, 0u);
    __hip_atomic_store(accf, 0.0f, __ATOMIC_RELAXED, __HIP_MEMORY_SCOPE_AGENT);
    __builtin_amdgcn_s_waitcnt(0);         // zeros at LLC before flag
    AT_ST(flag, MAGIC);
  }

  // --- P0: class buckets (blocks 0..61), plain stores + LDS counter.
  // y_map entries unique => block c claims exactly the class-c samples.
  if (b < NCLS) {
    if (tid == 0) lcnt = 0;
    __syncthreads();
    const int ym = y_map[b];
    for (int j = tid; j < B_N; j += BLKT) {
      if (y_idx[j] == ym) {
        const int pos = atomicAdd(&lcnt, 1);     // LDS atomic
        if (pos < BCAP) bkt[b * BCAP + pos] = j; // plain store
      }
    }
    __syncthreads();
    if (tid == 0) cnt[b] = min(lcnt, BCAP);
  }

  // --- P1: GT[j][k] = p_hat_k . z_j, ROW-MAJOR stride 96, plain stores.
  // 16 j-chunks x 512 rows (1 row/thread), 16 k-tiles x 6 proxies (96 incl
  // 3 zero-pad). Tile 15 also computes zz/sz/w.
  const int jch = b & 15, kt = b >> 4, k0 = kt * 6;
  const int j = jch * 512 + tid;
  if (wv < 6) {                            // normalize 6 proxy rows into LDS
    const int k = k0 + wv;
    float a = 0.0f, c2 = 0.0f;
    if (k < P_N) { a = prox[k * Z_D + lane]; c2 = prox[k * Z_D + 64 + lane]; }
    const float s = wave_sum(a + c2);
    const float q = wave_sum(a * a + c2 * c2);
    float inv = 1.0f / fmaxf(sqrtf(q), 1e-12f);
    if (k >= P_N) inv = 0.0f;              // zero the pad rows 93..95
    pt[wv * Z_D + lane] = a * inv;
    pt[wv * Z_D + 64 + lane] = c2 * inv;
    if (jch == 0 && lane == 0 && k < P_N) {
      pp[k] = q * inv * inv;               // ||p_hat||^2
      sp[k] = s * inv;                     // sum(p_hat)
    }
  }
  __syncthreads();
  {
    float a0 = 0, a1 = 0, a2 = 0, a3 = 0, a4 = 0, a5 = 0;
    float zs = 0, zq = 0;
    const bool do_stats = (kt == 15);      // uniform branch
    const float* __restrict__ zrow = z + (size_t)j * Z_D;
#pragma unroll 8
    for (int i4 = 0; i4 < Z_D; i4 += 4) {
      const float4 zv = *(const float4*)(zrow + i4);
      if (do_stats) {
        zs += zv.x + zv.y + zv.z + zv.w;
        zq += zv.x * zv.x + zv.y * zv.y + zv.z * zv.z + zv.w * zv.w;
      }
      const float4 p0 = *(const float4*)(pt + 0 * Z_D + i4);  // LDS broadcast
      const float4 p1 = *(const float4*)(pt + 1 * Z_D + i4);
      const float4 p2 = *(const float4*)(pt + 2 * Z_D + i4);
      const float4 p3 = *(const float4*)(pt + 3 * Z_D + i4);
      const float4 p4 = *(const float4*)(pt + 4 * Z_D + i4);
      const float4 p5 = *(const float4*)(pt + 5 * Z_D + i4);
      a0 += zv.x * p0.x + zv.y * p0.y + zv.z * p0.z + zv.w * p0.w;
      a1 += zv.x * p1.x + zv.y * p1.y + zv.z * p1.z + zv.w * p1.w;
      a2 += zv.x * p2.x + zv.y * p2.y + zv.z * p2.z + zv.w * p2.w;
      a3 += zv.x * p3.x + zv.y * p3.y + zv.z * p3.z + zv.w * p3.w;
      a4 += zv.x * p4.x + zv.y * p4.y + zv.z * p4.z + zv.w * p4.w;
      a5 += zv.x * p5.x + zv.y * p5.y + zv.z * p5.z + zv.w * p5.w;
    }
    float* gtp = GT + (size_t)j * GT_S + k0;     // k0*4 % 8 == 0 -> aligned
    *(float2*)(gtp + 0) = make_float2(a0, a1);   // plain cached stores
    *(float2*)(gtp + 2) = make_float2(a2, a3);
    *(float2*)(gtp + 4) = make_float2(a4, a5);
    if (do_stats) {
      zz[j] = zq; sz[j] = zs; w[j] = zq - TWO_EPS * zs;
    }
  }

  // --- grid barrier: bulk-coherence protocol --------------------------------
  __syncthreads();                         // all block stores at L2
  if (tid == 0) {
    int g = 0;
    while (AT_LD(flag) != MAGIC) {         // wait init published (load probe)
      __builtin_amdgcn_s_sleep(2);
      if (++g > (1 << 22)) break;
    }
    __threadfence();                       // ONE buffer_wbl2: L2 dirty -> LLC
    AT_ADD(bar0, 1u);                      // arrive (RMW, 256 total)
    g = 0;
    while (AT_LD(bar0) < (unsigned)NBLK) { // read-only probes: no ownership
      __builtin_amdgcn_s_sleep(32);
      if (++g > (1 << 22)) break;
    }
    (void)AT_LDA(bar0);                    // ONE buffer_inv: L1/L2 refresh
  }
  __syncthreads();

  // --- P2 staging: proxy scalars + class map into LDS (plain, coherent) ---
  if (tid < P_N) { lpp[tid] = pp[tid]; lsp[tid] = sp[tid]; }
  if (tid < NCLS) lymap[tid] = y_map[tid];
  __syncthreads();

  // --- P2: one wave per anchor, all plain cached loads ---------------------
  float lsum = 0.0f;
  for (int wid = b * 8 + wv; wid < A_N; wid += NBLK * 8) {
    const int i = 3 * wid;
    const int yi = y_idx[i];
    const unsigned long long mm = __ballot(lane < NCLS && lymap[lane] == yi);
    const int cls = __ffsll(mm) - 1;       // unique match (y_map unique)
    const float zzi = zz[i], szi = sz[i];
    const int kB = lane + 64;

    // step a: nearest proxy (argmin, first-index tie-break)
    const float* __restrict__ GTi = GT + (size_t)i * GT_S;
    float v1 = fmaxf(zzi + lpp[lane] - 2.0f * GTi[lane] +
                     TWO_EPS * (szi - lsp[lane]) + ZEPS2, 0.0f);
    int i1 = lane;
    if (kB < P_N) {
      const float v2 = fmaxf(zzi + lpp[kB] - 2.0f * GTi[kB] +
                             TWO_EPS * (szi - lsp[kB]) + ZEPS2, 0.0f);
      if (v2 < v1) { v1 = v2; i1 = kB; }
    }
#pragma unroll
    for (int off = 1; off < 64; off <<= 1) {
      const float ov = __shfl_xor(v1, off, 64);
      const int oi = __shfl_xor(i1, off, 64);
      if (ov < v1 || (ov == v1 && oi < i1)) { v1 = ov; i1 = oi; }
    }
    const int p = i1;

    // step b: hardest positive in same-class suffix (bucket scan)
    const float cp = lpp[p] + TWO_EPS * lsp[p] + ZEPS2;
    const int n = cnt[cls];
    const int* __restrict__ bk = bkt + cls * BCAP;
    float best = -INFINITY;
    int bestj = 0x7fffffff;
    for (int t = lane; t < n; t += 64) {
      const int jj = bk[t];
      if (jj >= i) {
        const float vv = fmaxf(cp + w[jj] - 2.0f * GT[(size_t)jj * GT_S + p], 0.0f);
        if (vv > best || (vv == best && jj < bestj)) { best = vv; bestj = jj; }
      }
    }
#pragma unroll
    for (int off = 1; off < 64; off <<= 1) {
      const float ov = __shfl_xor(best, off, 64);
      const int oj = __shfl_xor(bestj, off, 64);
      if (ov > best || (ov == best && oj < bestj)) { best = ov; bestj = oj; }
    }
    const float Dp = sqrtf(best);
    const int jp = bestj;

    // step c: logsumexp(-D_n) over proxies
    const float zzj = zz[jp], szj = sz[jp];
    const float* __restrict__ GTj = GT + (size_t)jp * GT_S;
    const float d1 = sqrtf(fmaxf(zzj + lpp[lane] - 2.0f * GTj[lane] +
                                 TWO_EPS * (szj - lsp[lane]) + ZEPS2, 0.0f));
    float d2 = INFINITY;
    if (kB < P_N)
      d2 = sqrtf(fmaxf(zzj + lpp[kB] - 2.0f * GTj[kB] +
                       TWO_EPS * (szj - lsp[kB]) + ZEPS2, 0.0f));
    const float mn = wave_min(fminf(d1, d2));
    float ss = expf(mn - d1) + ((kB < P_N) ? expf(mn - d2) : 0.0f);
    ss = wave_sum(ss);
    lsum += Dp - mn + logf(ss);
  }
  if (lane == 0) part[wv] = lsum;
  __syncthreads();

  // --- finalize: block partial -> LLC add; LAST arriver writes the mean ---
  if (tid == 0) {
    const float tot = part[0] + part[1] + part[2] + part[3] +
                      part[4] + part[5] + part[6] + part[7];
    AT_ADD(accf, tot);
    __builtin_amdgcn_s_waitcnt(0);         // our add completed at LLC
    const unsigned old = AT_ADD(bar1, 1u);
    if (old == (unsigned)(NBLK - 1))       // all 256 adds are in
      out[0] = AT_ADD(accf, 0.0f) * (1.0f / (float)A_N);
  }
}

extern "C" void kernel_launch(void* const* d_in, const int* in_sizes, int n_in,
                              void* d_out, int out_size, void* d_ws, size_t ws_size,
                              hipStream_t stream) {
  const float* z = (const float*)d_in[0];      // [8192,128] f32
  const int* y_idx = (const int*)d_in[1];      // [8192] i32
  const float* prox = (const float*)d_in[2];   // [93,128] f32
  const int* y_map = (const int*)d_in[3];      // [62] i32
  float* out = (float*)d_out;

  // workspace layout (bytes), ~3.25 MB
  char* ws = (char*)d_ws;
  unsigned int* flag = (unsigned int*)(ws + 0);   // separate cache lines
  unsigned int* bar0 = (unsigned int*)(ws + 128);
  unsigned int* bar1 = (unsigned int*)(ws + 256);
  float* accf = (float*)(ws + 384);
  float* pp   = (float*)(ws + 512);            // 93*4 (pad 512)
  float* sp   = (float*)(ws + 1024);           // 93*4 (pad 512)
  float* zz   = (float*)(ws + 1536);           // 8192*4 -> 34304
  float* sz   = (float*)(ws + 34304);          // -> 67072
  float* w    = (float*)(ws + 67072);          // -> 99840
  int*   cnt  = (int*)  (ws + 99840);          // 62*4 (pad 256) -> 100096
  int*   bkt  = (int*)  (ws + 100096);         // 62*256*4 -> 163584
  float* GT   = (float*)(ws + 163584);         // 8192*96*4 row-major -> 3309312

  kFused<<<NBLK, BLKT, 0, stream>>>(z, y_idx, prox, y_map, out,
                                    flag, bar0, bar1, accf,
                                    pp, sp, zz, sz, w, cnt, bkt, GT);
}

// Round 7
// 90.934 us; speedup vs baseline: 1.2075x; 1.2075x over previous
//
#include <hip/hip_runtime.h>
#include <math.h>

// Problem constants (match reference setup_inputs)
#define B_N   8192      // samples
#define Z_D   128       // feature dim
#define P_N   93        // proxies
#define NCLS  62        // classes
#define A_N   2730      // anchors: arange(0, 8189, 3)
#define BCAP  256       // class-bucket capacity (max expected ~180)
#define GT_S  96        // GT row stride
#define NPART 683       // ceil(A_N / 4) = kB2 grid
#define TWO_EPS   2e-6f
#define ZEPS2     (128.0f * 1e-6f * 1e-6f)

__device__ __forceinline__ float wave_sum(float v) {
#pragma unroll
  for (int off = 1; off < 64; off <<= 1) v += __shfl_xor(v, off, 64);
  return v;
}
__device__ __forceinline__ float wave_min(float v) {
#pragma unroll
  for (int off = 1; off < 64; off <<= 1) v = fminf(v, __shfl_xor(v, off, 64));
  return v;
}

// --- kA: blocks 0..255 compute GT rows (P1); blocks 256..317 build class
// buckets (P0). Kernel boundary provides the coherent barrier for free. ----
__global__ __launch_bounds__(512) void kA(
    const float* __restrict__ z, const int* __restrict__ y_idx,
    const float* __restrict__ prox, const int* __restrict__ y_map,
    float* __restrict__ pp, float* __restrict__ sp,
    float* __restrict__ zz, float* __restrict__ sz,
    int* __restrict__ cnt, int2* __restrict__ bkt, float* __restrict__ GT) {
  __shared__ float linv[6];
  __shared__ int lmem[BCAP];
  __shared__ int lcnt;
  const int b = blockIdx.x, tid = threadIdx.x;
  const int lane = tid & 63, wv = tid >> 6;

  if (b < 256) {
    // --- P1: 16 j-chunks x 512 rows (1 row/thread), 16 k-tiles.
    // Tiles 0..14: 6 proxies; tile 15: proxies 90..92 + z row stats.
    const int jch = b & 15, kt = b >> 4, k0 = kt * 6;
    const int nk = (kt == 15) ? 3 : 6;
    const int j = jch * 512 + tid;
    const float* __restrict__ zrow = z + (size_t)j * Z_D;
    if (wv < nk) {                         // per-proxy norm via wave reduce
      const int k = k0 + wv;
      const float a = prox[k * Z_D + lane];
      const float c = prox[k * Z_D + 64 + lane];
      const float s = wave_sum(a + c);
      const float q = wave_sum(a * a + c * c);
      const float inv = 1.0f / fmaxf(sqrtf(q), 1e-12f);
      if (lane == 0) {
        linv[wv] = inv;
        if (jch == 0) { pp[k] = q * inv * inv; sp[k] = s * inv; }
      }
    }
    __syncthreads();
    if (kt < 15) {
      // raw dots vs 6 proxies; proxy addresses are wave-uniform -> s_loads
      const float* __restrict__ p0 = prox + (size_t)(k0 + 0) * Z_D;
      const float* __restrict__ p1 = prox + (size_t)(k0 + 1) * Z_D;
      const float* __restrict__ p2 = prox + (size_t)(k0 + 2) * Z_D;
      const float* __restrict__ p3 = prox + (size_t)(k0 + 3) * Z_D;
      const float* __restrict__ p4 = prox + (size_t)(k0 + 4) * Z_D;
      const float* __restrict__ p5 = prox + (size_t)(k0 + 5) * Z_D;
      float a0 = 0, a1 = 0, a2 = 0, a3 = 0, a4 = 0, a5 = 0;
#pragma unroll 8
      for (int i4 = 0; i4 < Z_D; i4 += 4) {
        const float4 zv = *(const float4*)(zrow + i4);
        const float4 q0 = *(const float4*)(p0 + i4);
        const float4 q1 = *(const float4*)(p1 + i4);
        const float4 q2 = *(const float4*)(p2 + i4);
        const float4 q3 = *(const float4*)(p3 + i4);
        const float4 q4 = *(const float4*)(p4 + i4);
        const float4 q5 = *(const float4*)(p5 + i4);
        a0 += zv.x * q0.x + zv.y * q0.y + zv.z * q0.z + zv.w * q0.w;
        a1 += zv.x * q1.x + zv.y * q1.y + zv.z * q1.z + zv.w * q1.w;
        a2 += zv.x * q2.x + zv.y * q2.y + zv.z * q2.z + zv.w * q2.w;
        a3 += zv.x * q3.x + zv.y * q3.y + zv.z * q3.z + zv.w * q3.w;
        a4 += zv.x * q4.x + zv.y * q4.y + zv.z * q4.z + zv.w * q4.w;
        a5 += zv.x * q5.x + zv.y * q5.y + zv.z * q5.z + zv.w * q5.w;
      }
      const float v0 = linv[0], v1 = linv[1], v2 = linv[2];
      const float v3 = linv[3], v4 = linv[4], v5 = linv[5];
      float* g = GT + (size_t)j * GT_S + k0;       // k0 even -> 8B aligned
      *(float2*)(g + 0) = make_float2(a0 * v0, a1 * v1);
      *(float2*)(g + 2) = make_float2(a2 * v2, a3 * v3);
      *(float2*)(g + 4) = make_float2(a4 * v4, a5 * v5);
    } else {
      const float* __restrict__ p0 = prox + (size_t)90 * Z_D;
      const float* __restrict__ p1 = prox + (size_t)91 * Z_D;
      const float* __restrict__ p2 = prox + (size_t)92 * Z_D;
      float a0 = 0, a1 = 0, a2 = 0, zs = 0, zq = 0;
#pragma unroll 8
      for (int i4 = 0; i4 < Z_D; i4 += 4) {
        const float4 zv = *(const float4*)(zrow + i4);
        const float4 q0 = *(const float4*)(p0 + i4);
        const float4 q1 = *(const float4*)(p1 + i4);
        const float4 q2 = *(const float4*)(p2 + i4);
        zs += zv.x + zv.y + zv.z + zv.w;
        zq += zv.x * zv.x + zv.y * zv.y + zv.z * zv.z + zv.w * zv.w;
        a0 += zv.x * q0.x + zv.y * q0.y + zv.z * q0.z + zv.w * q0.w;
        a1 += zv.x * q1.x + zv.y * q1.y + zv.z * q1.z + zv.w * q1.w;
        a2 += zv.x * q2.x + zv.y * q2.y + zv.z * q2.z + zv.w * q2.w;
      }
      float* g = GT + (size_t)j * GT_S + 90;       // 90 even -> 8B aligned
      *(float2*)(g) = make_float2(a0 * linv[0], a1 * linv[1]);
      g[2] = a2 * linv[2];
      zz[j] = zq;
      sz[j] = zs;
    }
  } else {
    // --- P0: class c = b-256 claims its samples (y_map unique), packs
    // (j, w_j = zz_j - 2*eps*sz_j) into bucket entries. LDS atomics only.
    const int c = b - 256;
    if (tid == 0) lcnt = 0;
    __syncthreads();
    const int ym = y_map[c];
    for (int j = tid; j < B_N; j += 512) {
      if (y_idx[j] == ym) {
        const int pos = atomicAdd(&lcnt, 1);
        if (pos < BCAP) lmem[pos] = j;
      }
    }
    __syncthreads();
    const int n = min(lcnt, BCAP);
    if (tid == 0) cnt[c] = n;
    for (int m = wv; m < n; m += 8) {      // one member per wave, round-robin
      const int j = lmem[m];
      const float a = z[(size_t)j * Z_D + lane];
      const float c2 = z[(size_t)j * Z_D + 64 + lane];
      const float s = wave_sum(a + c2);
      const float q = wave_sum(a * a + c2 * c2);
      if (lane == 0)
        bkt[c * BCAP + m] = make_int2(j, __float_as_int(q - TWO_EPS * s));
    }
  }
}

// --- kB2: one wave per anchor; 4 waves/block, 683 blocks (~10.7 waves/CU).
// Per-block partial loss to an array — zero global atomics. -----------------
__global__ __launch_bounds__(256) void kB2(
    const int* __restrict__ y_idx, const int* __restrict__ y_map,
    const float* __restrict__ pp, const float* __restrict__ sp,
    const float* __restrict__ zz, const float* __restrict__ sz,
    const int* __restrict__ cnt, const int2* __restrict__ bkt,
    const float* __restrict__ GT, float* __restrict__ partial) {
  __shared__ float lpp[P_N], lsp[P_N];
  __shared__ int lymap[NCLS];
  __shared__ float part[4];
  const int tid = threadIdx.x, lane = tid & 63, wv = tid >> 6;
  if (tid < P_N) { lpp[tid] = pp[tid]; lsp[tid] = sp[tid]; }
  if (tid < NCLS) lymap[tid] = y_map[tid];
  __syncthreads();

  const int wid = blockIdx.x * 4 + wv;
  float loss = 0.0f;
  if (wid < A_N) {
    const int i = 3 * wid;
    const int yi = y_idx[i];
    const unsigned long long mm = __ballot(lane < NCLS && lymap[lane] == yi);
    const int cls = __ffsll(mm) - 1;       // unique match (y_map unique)
    const float zzi = zz[i], szi = sz[i];
    const int kB = lane + 64;

    // step a: nearest proxy (argmin, first-index tie-break)
    const float* __restrict__ GTi = GT + (size_t)i * GT_S;
    float v1 = fmaxf(zzi + lpp[lane] - 2.0f * GTi[lane] +
                     TWO_EPS * (szi - lsp[lane]) + ZEPS2, 0.0f);
    int i1 = lane;
    if (kB < P_N) {
      const float v2 = fmaxf(zzi + lpp[kB] - 2.0f * GTi[kB] +
                             TWO_EPS * (szi - lsp[kB]) + ZEPS2, 0.0f);
      if (v2 < v1) { v1 = v2; i1 = kB; }
    }
#pragma unroll
    for (int off = 1; off < 64; off <<= 1) {
      const float ov = __shfl_xor(v1, off, 64);
      const int oi = __shfl_xor(i1, off, 64);
      if (ov < v1 || (ov == v1 && oi < i1)) { v1 = ov; i1 = oi; }
    }
    const int p = i1;

    // step b: hardest positive in same-class suffix; bucket entry carries
    // (j, w_j) in one 8B load -> single dependent gather on GT.
    const float cp = lpp[p] + TWO_EPS * lsp[p] + ZEPS2;
    const int n = cnt[cls];
    const int2* __restrict__ bk = bkt + cls * BCAP;
    float best = -INFINITY;
    int bestj = 0x7fffffff;
    for (int t = lane; t < n; t += 64) {
      const int2 e = bk[t];
      const int jj = e.x;
      if (jj >= i) {
        const float vv = fmaxf(cp + __int_as_float(e.y) -
                               2.0f * GT[(size_t)jj * GT_S + p], 0.0f);
        if (vv > best || (vv == best && jj < bestj)) { best = vv; bestj = jj; }
      }
    }
#pragma unroll
    for (int off = 1; off < 64; off <<= 1) {
      const float ov = __shfl_xor(best, off, 64);
      const int oj = __shfl_xor(bestj, off, 64);
      if (ov > best || (ov == best && oj < bestj)) { best = ov; bestj = oj; }
    }
    const float Dp = sqrtf(best);
    const int jp = bestj;

    // step c: logsumexp(-D_n) over proxies
    const float zzj = zz[jp], szj = sz[jp];
    const float* __restrict__ GTj = GT + (size_t)jp * GT_S;
    const float d1 = sqrtf(fmaxf(zzj + lpp[lane] - 2.0f * GTj[lane] +
                                 TWO_EPS * (szj - lsp[lane]) + ZEPS2, 0.0f));
    float d2 = INFINITY;
    if (kB < P_N)
      d2 = sqrtf(fmaxf(zzj + lpp[kB] - 2.0f * GTj[kB] +
                       TWO_EPS * (szj - lsp[kB]) + ZEPS2, 0.0f));
    const float mn = wave_min(fminf(d1, d2));
    float ss = expf(mn - d1) + ((kB < P_N) ? expf(mn - d2) : 0.0f);
    ss = wave_sum(ss);
    loss = Dp - mn + logf(ss);
  }
  if (lane == 0) part[wv] = (wid < A_N) ? loss : 0.0f;
  __syncthreads();
  if (tid == 0)
    partial[blockIdx.x] = part[0] + part[1] + part[2] + part[3];
}

// --- kC2: reduce 683 partials -> mean --------------------------------------
__global__ __launch_bounds__(256) void kC2(const float* __restrict__ partial,
                                           float* __restrict__ out) {
  __shared__ float ps[4];
  const int tid = threadIdx.x, lane = tid & 63, wv = tid >> 6;
  float s = 0.0f;
  for (int i = tid; i < NPART; i += 256) s += partial[i];
  s = wave_sum(s);
  if (lane == 0) ps[wv] = s;
  __syncthreads();
  if (tid == 0)
    out[0] = (ps[0] + ps[1] + ps[2] + ps[3]) * (1.0f / (float)A_N);
}

extern "C" void kernel_launch(void* const* d_in, const int* in_sizes, int n_in,
                              void* d_out, int out_size, void* d_ws, size_t ws_size,
                              hipStream_t stream) {
  const float* z = (const float*)d_in[0];      // [8192,128] f32
  const int* y_idx = (const int*)d_in[1];      // [8192] i32
  const float* prox = (const float*)d_in[2];   // [93,128] f32
  const int* y_map = (const int*)d_in[3];      // [62] i32
  float* out = (float*)d_out;

  // workspace layout (bytes), ~3.34 MB
  char* ws = (char*)d_ws;
  float* pp    = (float*)(ws + 0);             // 93*4 (pad 512)
  float* sp    = (float*)(ws + 512);           // 93*4 (pad 512) -> 1024
  float* zz    = (float*)(ws + 1024);          // 8192*4 -> 33792
  float* sz    = (float*)(ws + 33792);         // -> 66560
  int*   cnt   = (int*)  (ws + 66560);         // 62*4 (pad 256) -> 66816
  int2*  bkt   = (int2*) (ws + 66816);         // 62*256*8 -> 193792
  float* parts = (float*)(ws + 193792);        // 683*4 (pad) -> 196608
  float* GT    = (float*)(ws + 196608);        // 8192*96*4 -> 3342336

  kA<<<256 + NCLS, 512, 0, stream>>>(z, y_idx, prox, y_map,
                                     pp, sp, zz, sz, cnt, bkt, GT);
  kB2<<<NPART, 256, 0, stream>>>(y_idx, y_map, pp, sp, zz, sz,
                                 cnt, bkt, GT, parts);
  kC2<<<1, 256, 0, stream>>>(parts, out);
}